// Round 5
// baseline (3157.159 us; speedup 1.0000x reference)
//
#include <hip/hip_runtime.h>

// B=4, T=2048, C=1024, V=50257
// loss = mean_i [ log(sum_v exp(x_i.W_v + b_v)) - (x_i.W_{y_i} + b_{y_i}) ]
// R5: no-LDS fp8 GEMM, 128x128 wave tile (4x4 mfma 32x32x64, 256-reg acc),
// 1 wave/SIMD, explicit register prefetch pipeline. 128 FLOP/B fragment
// traffic balances L1 (64 B/cyc/CU) against the matrix pipe.

#define M_TOT 8192
#define K_TOT 1024
#define V_TOT 50257
#define NVB   197                // vocab blocks of 256
#define NPAD  (NVB * 256)        // 50432
#define PSTRIDE (NVB * 2)        // 394 partials per batch row
#define KB    (K_TOT / 64)       // 16 K-blocks of 64
#define GSTRIDE ((long)KB * 64 * 32)   // bytes per packed 32-row group

typedef __attribute__((ext_vector_type(8)))  int   int8v;
typedef __attribute__((ext_vector_type(16))) float floatx16;

__device__ __forceinline__ int f4_to_fp8x4(float4 v) {
  int r = __builtin_amdgcn_cvt_pk_fp8_f32(v.x, v.y, 0, false);
  r = __builtin_amdgcn_cvt_pk_fp8_f32(v.z, v.w, r, true);
  return r;
}

// Packed layout (verified R3/R4): for 32-row group g, K-block kb, MFMA lane
// l = h*32 + r (h = k-half, r = row-in-group), byte c in 0..31:
//   p[((g*KB+kb)*64 + l)*32 + c] = fp8(src[g*32 + r][kb*64 + h*32 + c])
// One merged launch packs both x and W. Block = one (kb, group).
__global__ __launch_bounds__(256) void pack_kernel(
    const float* __restrict__ x, const float* __restrict__ W,
    char* __restrict__ pX, char* __restrict__ pW) {
  const int kb = blockIdx.x;
  int g = blockIdx.y;
  const float* src; char* dst; int nrows;
  if (g < M_TOT / 32) { src = x; dst = pX; nrows = M_TOT; }
  else { g -= M_TOT / 32; src = W; dst = pW; nrows = V_TOT; }
  const int i = threadIdx.x;
  const int r = i >> 3, seg = i & 7;
  const int srow = g * 32 + r;
  int lo = 0, hi = 0;
  if (srow < nrows) {
    const float4* s = (const float4*)(src + (long)srow * K_TOT + kb * 64 + seg * 8);
    lo = f4_to_fp8x4(s[0]);
    hi = f4_to_fp8x4(s[1]);
  }
  const int h = seg >> 2;
  char* d = dst + (((long)(g * KB + kb) * 64 + h * 32 + r) * 32 + (seg & 3) * 8);
  *(int2*)d = make_int2(lo, hi);
}

// Block tile: 256 vocab x 256 batch, 4 waves 2x2 (wv, wb); each wave
// 128x128 via 4x4 mfma_scale_f32_32x32x64_f8f6f4 (unit scales = plain fp8).
// Per (group, kb) a wave reads one contiguous 2KB span; kb+1 fragments are
// prefetched into registers while kb's 16 MFMAs (~1100 SIMD-cyc) execute.
__global__ __launch_bounds__(256, 1) void gemm_lse_kernel(
    const char* __restrict__ pW, const char* __restrict__ pX,
    const float* __restrict__ bias, float* __restrict__ psum) {
  const int tid  = threadIdx.x;
  const int wave = tid >> 6;
  const int lane = tid & 63;
  const int wv   = wave >> 1;            // vocab half (128 rows)
  const int wb   = wave & 1;             // batch half (128 cols)
  const int mblk = blockIdx.x;
  const int vblk = blockIdx.y;

  const char* pa[4];
  const char* pb[4];
#pragma unroll
  for (int tv = 0; tv < 4; ++tv)
    pa[tv] = pW + (long)(vblk * 8 + wv * 4 + tv) * GSTRIDE + (long)lane * 32;
#pragma unroll
  for (int tn = 0; tn < 4; ++tn)
    pb[tn] = pX + (long)(mblk * 8 + wb * 4 + tn) * GSTRIDE + (long)lane * 32;

  floatx16 acc[4][4] = {};
  int8v a[4], b[4];
#pragma unroll
  for (int j = 0; j < 4; ++j) {
    a[j] = *(const int8v*)(pa[j]);
    b[j] = *(const int8v*)(pb[j]);
  }
#pragma unroll
  for (int kb = 0; kb < KB; ++kb) {
    int8v an[4], bn[4];
    if (kb + 1 < KB) {
      const int off = (kb + 1) * 2048;
#pragma unroll
      for (int j = 0; j < 4; ++j) {
        an[j] = *(const int8v*)(pa[j] + off);
        bn[j] = *(const int8v*)(pb[j] + off);
      }
    }
#pragma unroll
    for (int tv = 0; tv < 4; ++tv)
#pragma unroll
      for (int tn = 0; tn < 4; ++tn)
        acc[tv][tn] = __builtin_amdgcn_mfma_scale_f32_32x32x64_f8f6f4(
            a[tv], b[tn], acc[tv][tn], 0, 0, 0, 0x7F7F7F7F, 0, 0x7F7F7F7F);
    if (kb + 1 < KB) {
#pragma unroll
      for (int j = 0; j < 4; ++j) { a[j] = an[j]; b[j] = bn[j]; }
    }
  }

  // Epilogue. C layout (verified R2-R4): col(batch) = l32,
  // row(vocab within 32-group) = (reg&3) + 8*(reg>>2) + 4*half.
  const int half = lane >> 5, l32 = lane & 31;
  const int vbase = vblk * 256 + wv * 128 + 4 * half;
  float s[4] = {0.0f, 0.0f, 0.0f, 0.0f};
#pragma unroll
  for (int tv = 0; tv < 4; ++tv) {
#pragma unroll
    for (int reg = 0; reg < 16; ++reg) {
      int v = vbase + tv * 32 + (reg & 3) + 8 * (reg >> 2);
      float bv = (v < V_TOT) ? bias[v] : -1e30f;   // exp -> 0 for pad rows
#pragma unroll
      for (int tn = 0; tn < 4; ++tn) s[tn] += __expf(acc[tv][tn][reg] + bv);
    }
  }
#pragma unroll
  for (int tn = 0; tn < 4; ++tn) s[tn] += __shfl_xor(s[tn], 32, 64);
  if (half == 0) {
#pragma unroll
    for (int tn = 0; tn < 4; ++tn) {
      int m = mblk * 256 + wb * 128 + tn * 32 + l32;
      psum[(long)m * PSTRIDE + vblk * 2 + wv] = s[tn];
    }
  }
}

// One wave per batch row: sum 394 partials -> log; exact fp32 label logit.
__global__ __launch_bounds__(256) void finalize_kernel(
    const float* __restrict__ psum, const float* __restrict__ x,
    const float* __restrict__ W, const float* __restrict__ b,
    const int* __restrict__ y, float* __restrict__ loss) {
  const int wave = threadIdx.x >> 6;
  const int lane = threadIdx.x & 63;
  const int r = blockIdx.x * 4 + wave;

  const float* ps = psum + (long)r * PSTRIDE;
  float s = 0.0f;
  for (int j = lane; j < PSTRIDE; j += 64) s += ps[j];
#pragma unroll
  for (int o = 1; o < 64; o <<= 1) s += __shfl_xor(s, o, 64);

  int label = y[r];
  const float4* xr = (const float4*)(x + (long)r * K_TOT);
  const float4* wr = (const float4*)(W + (long)label * K_TOT);
  float d = 0.0f;
  for (int j = lane; j < K_TOT / 4; j += 64) {
    float4 a = xr[j], w = wr[j];
    d += a.x * w.x + a.y * w.y + a.z * w.z + a.w * w.w;
  }
#pragma unroll
  for (int o = 1; o < 64; o <<= 1) d += __shfl_xor(d, o, 64);

  if (lane == 0) loss[r] = logf(s) - d - b[label];
}

// Single block: deterministic mean of 8192 per-row losses.
__global__ __launch_bounds__(256) void reduce_kernel(
    const float* __restrict__ loss, float* __restrict__ out) {
  const int tid = threadIdx.x;
  float s = 0.0f;
  for (int j = tid; j < M_TOT; j += 256) s += loss[j];
#pragma unroll
  for (int o = 1; o < 64; o <<= 1) s += __shfl_xor(s, o, 64);
  __shared__ float wsum[4];
  if ((tid & 63) == 0) wsum[tid >> 6] = s;
  __syncthreads();
  if (tid == 0)
    out[0] = (wsum[0] + wsum[1] + wsum[2] + wsum[3]) * (1.0f / (float)M_TOT);
}

extern "C" void kernel_launch(void* const* d_in, const int* in_sizes, int n_in,
                              void* d_out, int out_size, void* d_ws, size_t ws_size,
                              hipStream_t stream) {
  (void)in_sizes; (void)n_in; (void)out_size; (void)ws_size;
  const float* x = (const float*)d_in[0];
  const int*   y = (const int*)d_in[1];
  const float* W = (const float*)d_in[2];
  const float* b = (const float*)d_in[3];
  float* out = (float*)d_out;

  char* ws = (char*)d_ws;
  const size_t PX_BYTES = (size_t)M_TOT * K_TOT;            // 8.4 MB
  const size_t PW_BYTES = (size_t)NPAD * K_TOT;             // 51.6 MB
  const size_t PS_BYTES = (size_t)M_TOT * PSTRIDE * 4;      // 12.9 MB
  char*  pX   = ws;
  char*  pW   = ws + PX_BYTES;
  float* psum = (float*)(ws + PX_BYTES + PW_BYTES);
  float* loss = (float*)(ws + PX_BYTES + PW_BYTES + PS_BYTES);

  pack_kernel<<<dim3(KB, M_TOT / 32 + NPAD / 32), 256, 0, stream>>>(x, W, pX, pW);
  gemm_lse_kernel<<<dim3(M_TOT / 256, NVB), 256, 0, stream>>>(pW, pX, b, psum);
  finalize_kernel<<<M_TOT / 4, 256, 0, stream>>>(psum, x, W, b, y, loss);
  reduce_kernel<<<1, 256, 0, stream>>>(loss, out);
}

// Round 6
// 1612.371 us; speedup vs baseline: 1.9581x; 1.9581x over previous
//
#include <hip/hip_runtime.h>

// B=4, T=2048, C=1024, V=50257
// loss = mean_i [ log(sum_v exp(x_i.W_v + b_v)) - (x_i.W_{y_i} + b_{y_i}) ]
// R6: no-LDS fp8 GEMM, 128x128 wave tile (4x4 mfma 32x32x64, 256 AGPR acc),
// 1 wave/SIMD. Bounded double-buffer (kb+=2, unroll 1): exactly 128 arch regs
// of fragments live -> no spill (R5 lesson: full unroll + prefetch spilled
// acc to scratch, 8.3 GB HBM traffic).

#define M_TOT 8192
#define K_TOT 1024
#define V_TOT 50257
#define NVB   197                // vocab blocks of 256
#define NPAD  (NVB * 256)        // 50432
#define PSTRIDE (NVB * 2)        // 394 partials per batch row
#define KB    (K_TOT / 64)       // 16 K-blocks of 64
#define GSTRIDE ((long)KB * 64 * 32)   // bytes per packed 32-row group

typedef __attribute__((ext_vector_type(8)))  int   int8v;
typedef __attribute__((ext_vector_type(16))) float floatx16;

__device__ __forceinline__ int f4_to_fp8x4(float4 v) {
  int r = __builtin_amdgcn_cvt_pk_fp8_f32(v.x, v.y, 0, false);
  r = __builtin_amdgcn_cvt_pk_fp8_f32(v.z, v.w, r, true);
  return r;
}

// Packed layout (verified R3-R5): for 32-row group g, K-block kb, MFMA lane
// l = h*32 + r (h = k-half, r = row-in-group), byte c in 0..31:
//   p[((g*KB+kb)*64 + l)*32 + c] = fp8(src[g*32 + r][kb*64 + h*32 + c])
// One merged launch packs both x and W. Block = one (kb, group).
__global__ __launch_bounds__(256) void pack_kernel(
    const float* __restrict__ x, const float* __restrict__ W,
    char* __restrict__ pX, char* __restrict__ pW) {
  const int kb = blockIdx.x;
  int g = blockIdx.y;
  const float* src; char* dst; int nrows;
  if (g < M_TOT / 32) { src = x; dst = pX; nrows = M_TOT; }
  else { g -= M_TOT / 32; src = W; dst = pW; nrows = V_TOT; }
  const int i = threadIdx.x;
  const int r = i >> 3, seg = i & 7;
  const int srow = g * 32 + r;
  int lo = 0, hi = 0;
  if (srow < nrows) {
    const float4* s = (const float4*)(src + (long)srow * K_TOT + kb * 64 + seg * 8);
    lo = f4_to_fp8x4(s[0]);
    hi = f4_to_fp8x4(s[1]);
  }
  const int h = seg >> 2;
  char* d = dst + (((long)(g * KB + kb) * 64 + h * 32 + r) * 32 + (seg & 3) * 8);
  *(int2*)d = make_int2(lo, hi);
}

#define MFMA8(ACC, A, B)                                              \
  _Pragma("unroll")                                                   \
  for (int tv = 0; tv < 4; ++tv)                                      \
    _Pragma("unroll")                                                 \
    for (int tn = 0; tn < 4; ++tn)                                    \
      ACC[tv][tn] = __builtin_amdgcn_mfma_scale_f32_32x32x64_f8f6f4(  \
          A[tv], B[tn], ACC[tv][tn], 0, 0, 0, 0x7F7F7F7F, 0, 0x7F7F7F7F);

// Block tile: 256 vocab x 256 batch, 4 waves 2x2 (wv, wb); each wave
// 128x128 via 4x4 mfma_scale_f32_32x32x64_f8f6f4 (unit scales = plain fp8).
// Per (group, kb) a wave reads one contiguous 2KB span (coalesced, L1/L2).
__global__ __launch_bounds__(256, 1) void gemm_lse_kernel(
    const char* __restrict__ pW, const char* __restrict__ pX,
    const float* __restrict__ bias, float* __restrict__ psum) {
  const int tid  = threadIdx.x;
  const int wave = tid >> 6;
  const int lane = tid & 63;
  const int wv   = wave >> 1;            // vocab half (128 rows)
  const int wb   = wave & 1;             // batch half (128 cols)
  const int mblk = blockIdx.x;
  const int vblk = blockIdx.y;

  const char* pa[4];
  const char* pb[4];
#pragma unroll
  for (int tv = 0; tv < 4; ++tv)
    pa[tv] = pW + (long)(vblk * 8 + wv * 4 + tv) * GSTRIDE + (long)lane * 32;
#pragma unroll
  for (int tn = 0; tn < 4; ++tn)
    pb[tn] = pX + (long)(mblk * 8 + wb * 4 + tn) * GSTRIDE + (long)lane * 32;

  floatx16 acc[4][4] = {};
  int8v a0[4], b0[4], a1[4], b1[4];
#pragma unroll
  for (int j = 0; j < 4; ++j) {
    a0[j] = *(const int8v*)(pa[j]);
    b0[j] = *(const int8v*)(pb[j]);
  }
#pragma unroll 1
  for (int kb = 0; kb < KB; kb += 2) {
    const int off1 = (kb + 1) * 2048;
#pragma unroll
    for (int j = 0; j < 4; ++j) {
      a1[j] = *(const int8v*)(pa[j] + off1);
      b1[j] = *(const int8v*)(pb[j] + off1);
    }
    MFMA8(acc, a0, b0);
    if (kb + 2 < KB) {
      const int off2 = (kb + 2) * 2048;
#pragma unroll
      for (int j = 0; j < 4; ++j) {
        a0[j] = *(const int8v*)(pa[j] + off2);
        b0[j] = *(const int8v*)(pb[j] + off2);
      }
    }
    MFMA8(acc, a1, b1);
  }

  // Epilogue. C layout (verified R2-R4): col(batch) = l32,
  // row(vocab within 32-group) = (reg&3) + 8*(reg>>2) + 4*half.
  const int half = lane >> 5, l32 = lane & 31;
  const int vbase = vblk * 256 + wv * 128 + 4 * half;
  float s[4] = {0.0f, 0.0f, 0.0f, 0.0f};
#pragma unroll
  for (int tv = 0; tv < 4; ++tv) {
#pragma unroll
    for (int reg = 0; reg < 16; ++reg) {
      int v = vbase + tv * 32 + (reg & 3) + 8 * (reg >> 2);
      float bv = (v < V_TOT) ? bias[v] : -1e30f;   // exp -> 0 for pad rows
#pragma unroll
      for (int tn = 0; tn < 4; ++tn) s[tn] += __expf(acc[tv][tn][reg] + bv);
    }
  }
#pragma unroll
  for (int tn = 0; tn < 4; ++tn) s[tn] += __shfl_xor(s[tn], 32, 64);
  if (half == 0) {
#pragma unroll
    for (int tn = 0; tn < 4; ++tn) {
      int m = mblk * 256 + wb * 128 + tn * 32 + l32;
      psum[(long)m * PSTRIDE + vblk * 2 + wv] = s[tn];
    }
  }
}

// One wave per batch row: sum 394 partials -> log; exact fp32 label logit.
__global__ __launch_bounds__(256) void finalize_kernel(
    const float* __restrict__ psum, const float* __restrict__ x,
    const float* __restrict__ W, const float* __restrict__ b,
    const int* __restrict__ y, float* __restrict__ loss) {
  const int wave = threadIdx.x >> 6;
  const int lane = threadIdx.x & 63;
  const int r = blockIdx.x * 4 + wave;

  const float* ps = psum + (long)r * PSTRIDE;
  float s = 0.0f;
  for (int j = lane; j < PSTRIDE; j += 64) s += ps[j];
#pragma unroll
  for (int o = 1; o < 64; o <<= 1) s += __shfl_xor(s, o, 64);

  int label = y[r];
  const float4* xr = (const float4*)(x + (long)r * K_TOT);
  const float4* wr = (const float4*)(W + (long)label * K_TOT);
  float d = 0.0f;
  for (int j = lane; j < K_TOT / 4; j += 64) {
    float4 a = xr[j], w = wr[j];
    d += a.x * w.x + a.y * w.y + a.z * w.z + a.w * w.w;
  }
#pragma unroll
  for (int o = 1; o < 64; o <<= 1) d += __shfl_xor(d, o, 64);

  if (lane == 0) loss[r] = logf(s) - d - b[label];
}

// Single block: deterministic mean of 8192 per-row losses.
__global__ __launch_bounds__(256) void reduce_kernel(
    const float* __restrict__ loss, float* __restrict__ out) {
  const int tid = threadIdx.x;
  float s = 0.0f;
  for (int j = tid; j < M_TOT; j += 256) s += loss[j];
#pragma unroll
  for (int o = 1; o < 64; o <<= 1) s += __shfl_xor(s, o, 64);
  __shared__ float wsum[4];
  if ((tid & 63) == 0) wsum[tid >> 6] = s;
  __syncthreads();
  if (tid == 0)
    out[0] = (wsum[0] + wsum[1] + wsum[2] + wsum[3]) * (1.0f / (float)M_TOT);
}

extern "C" void kernel_launch(void* const* d_in, const int* in_sizes, int n_in,
                              void* d_out, int out_size, void* d_ws, size_t ws_size,
                              hipStream_t stream) {
  (void)in_sizes; (void)n_in; (void)out_size; (void)ws_size;
  const float* x = (const float*)d_in[0];
  const int*   y = (const int*)d_in[1];
  const float* W = (const float*)d_in[2];
  const float* b = (const float*)d_in[3];
  float* out = (float*)d_out;

  char* ws = (char*)d_ws;
  const size_t PX_BYTES = (size_t)M_TOT * K_TOT;            // 8.4 MB
  const size_t PW_BYTES = (size_t)NPAD * K_TOT;             // 51.6 MB
  const size_t PS_BYTES = (size_t)M_TOT * PSTRIDE * 4;      // 12.9 MB
  char*  pX   = ws;
  char*  pW   = ws + PX_BYTES;
  float* psum = (float*)(ws + PX_BYTES + PW_BYTES);
  float* loss = (float*)(ws + PX_BYTES + PW_BYTES + PS_BYTES);

  pack_kernel<<<dim3(KB, M_TOT / 32 + NPAD / 32), 256, 0, stream>>>(x, W, pX, pW);
  gemm_lse_kernel<<<dim3(M_TOT / 256, NVB), 256, 0, stream>>>(pW, pX, b, psum);
  finalize_kernel<<<M_TOT / 4, 256, 0, stream>>>(psum, x, W, b, y, loss);
  reduce_kernel<<<1, 256, 0, stream>>>(loss, out);
}